// Round 1
// baseline (690.386 us; speedup 1.0000x reference)
//
#include <hip/hip_runtime.h>
#include <cstdint>
#include <cstddef>

typedef unsigned short u16;
typedef __attribute__((ext_vector_type(8))) __bf16 bf16x8;
typedef __attribute__((ext_vector_type(4))) float f32x4;

#define MFMA(a, b, c) __builtin_amdgcn_mfma_f32_16x16x32_bf16(a, b, c, 0, 0, 0)

__device__ __forceinline__ u16 f2bf(float f) {
  union { float f; uint32_t u; } x; x.f = f;
  uint32_t r = x.u + 0x7fffu + ((x.u >> 16) & 1u);
  return (u16)(r >> 16);
}

__device__ __forceinline__ void gld16(const u16* g, u16* l) {
  __builtin_amdgcn_global_load_lds(
      (const __attribute__((address_space(1))) void*)g,
      (__attribute__((address_space(3))) void*)l, 16, 0, 0);
}

// ---------------- elementwise f32 -> bf16 convert ----------------
__global__ void cvt_f32_bf16(const float* __restrict__ src, u16* __restrict__ dst, int n4) {
  int i = blockIdx.x * blockDim.x + threadIdx.x;
  int stride = gridDim.x * blockDim.x;
  for (; i < n4; i += stride) {
    float4 v = ((const float4*)src)[i];
    ushort4 o;
    o.x = f2bf(v.x); o.y = f2bf(v.y); o.z = f2bf(v.z); o.w = f2bf(v.w);
    ((ushort4*)dst)[i] = o;
  }
}

// ---------------- transpose + convert: src (R x C) f32 -> dst (C x R) bf16 ----------------
__global__ void transpose_cvt(const float* __restrict__ src, u16* __restrict__ dst, int R, int C) {
  __shared__ float tile[32][33];
  int bx = blockIdx.x * 32, by = blockIdx.y * 32;
  int tx = threadIdx.x, ty = threadIdx.y;
  #pragma unroll
  for (int i = ty; i < 32; i += 8)
    tile[i][tx] = src[(size_t)(by + i) * C + bx + tx];
  __syncthreads();
  #pragma unroll
  for (int i = ty; i < 32; i += 8)
    dst[(size_t)(bx + i) * R + by + tx] = f2bf(tile[tx][i]);
}

// ---------------- KV prep: k normalized * temp * log2e -> (H,512,64); v -> V^T (H,64,512) ----------------
__global__ void kv_prep(const float* __restrict__ bank, const float* __restrict__ Wkv,
                        const float* __restrict__ temp, u16* __restrict__ K, u16* __restrict__ VT) {
  int m = blockIdx.x & 511, h = blockIdx.x >> 9;
  int j = threadIdx.x;  // 64 threads = d index
  const float* br = bank + m * 16;
  float kj = 0.f, vj = 0.f;
  #pragma unroll
  for (int f = 0; f < 16; ++f) {
    float bv = br[f];
    kj = fmaf(bv, Wkv[f * 1536 + h * 64 + j], kj);
    vj = fmaf(bv, Wkv[f * 1536 + 768 + h * 64 + j], vj);
  }
  float ss = kj * kj;
  #pragma unroll
  for (int o = 32; o; o >>= 1) ss += __shfl_xor(ss, o);
  float rn = rsqrtf(fmaxf(ss, 1e-24f));
  K[((size_t)h * 512 + m) * 64 + j] = f2bf(kj * rn * temp[h] * 1.4426950408889634f);
  VT[((size_t)h * 64 + j) * 512 + m] = f2bf(vj);
}

// ---------------- bf16 GEMM, A (MxK) row-major, BT (NxK) row-major ----------------
// MODE 0: write bf16 C. MODE 1: write fp32 C with +bias then PReLU.
template <int MODE>
__global__ __launch_bounds__(256, 3) void gemm_bt(
    const u16* __restrict__ A, const u16* __restrict__ BT, void* __restrict__ Cout,
    int M, int N, int K, const float* __restrict__ bias, const float* __restrict__ prelu) {
  __shared__ u16 sA[128 * 32];
  __shared__ u16 sB[128 * 32];
  const int ntiles = N >> 7;
  const int m0 = (blockIdx.x / ntiles) << 7;
  const int n0 = (blockIdx.x % ntiles) << 7;
  const int tid = threadIdx.x;
  const int w = tid >> 6, lane = tid & 63;
  const int wm = (w >> 1) << 6, wn = (w & 1) << 6;
  const int srow = lane >> 2, scol = (lane & 3) << 3;
  const u16* ga = A + (size_t)(m0 + (w << 5) + srow) * K + scol;
  const u16* gb = BT + (size_t)(n0 + (w << 5) + srow) * K + scol;
  u16* la = sA + (w << 5) * 32;
  u16* lb = sB + (w << 5) * 32;
  const int fr = lane & 15, fq = (lane >> 4) << 3;
  f32x4 acc[4][4] = {};

  for (int k0 = 0; k0 < K; k0 += 32) {
    __syncthreads();
    gld16(ga + k0, la);
    gld16(ga + k0 + (size_t)16 * K, la + 16 * 32);
    gld16(gb + k0, lb);
    gld16(gb + k0 + (size_t)16 * K, lb + 16 * 32);
    __syncthreads();
    bf16x8 af[4], bfr[4];
    #pragma unroll
    for (int t = 0; t < 4; ++t) {
      af[t] = *(const bf16x8*)(sA + (wm + t * 16 + fr) * 32 + fq);
      bfr[t] = *(const bf16x8*)(sB + (wn + t * 16 + fr) * 32 + fq);
    }
    #pragma unroll
    for (int i = 0; i < 4; ++i)
      #pragma unroll
      for (int j = 0; j < 4; ++j)
        acc[i][j] = MFMA(af[i], bfr[j], acc[i][j]);
  }

  const int q = lane >> 4;
  float a = (MODE == 1) ? prelu[0] : 0.f;
  #pragma unroll
  for (int tm = 0; tm < 4; ++tm)
    #pragma unroll
    for (int tn = 0; tn < 4; ++tn) {
      int col = n0 + wn + tn * 16 + fr;
      float bv = (MODE == 1) ? bias[col] : 0.f;
      #pragma unroll
      for (int r = 0; r < 4; ++r) {
        int row = m0 + wm + tm * 16 + q * 4 + r;
        float v = acc[tm][tn][r];
        if (MODE == 1) {
          v += bv;
          v = v >= 0.f ? v : v * a;
          ((float*)Cout)[(size_t)row * N + col] = v;
        } else {
          ((u16*)Cout)[(size_t)row * N + col] = f2bf(v);
        }
      }
    }
}

// ---------------- fused cosine attention ----------------
// grid: b*12*64 + h*64 + nt. Block 256 = 4 waves; wave w owns q-rows nt*64+w*16 .. +16.
// Q: (B*N, 768) bf16 (un-normalized; normalized on load). K: (H,512,64) bf16 (temp*log2e folded).
// VT: (H,64,512) bf16. O: (B*N,768) bf16.
__global__ __launch_bounds__(256, 2) void attn_kern(
    const u16* __restrict__ Q, const u16* __restrict__ Kb,
    const u16* __restrict__ Vt, u16* __restrict__ O) {
  __shared__ u16 sp[4][16 * 136];  // per-wave P staging, pad to 136 (272B rows, 16B aligned)
  __shared__ float lbuf[4][16];
  const int nt = blockIdx.x & 63;
  const int h = (blockIdx.x >> 6) % 12;
  const int b = blockIdx.x / 768;
  const int tid = threadIdx.x, w = tid >> 6, lane = tid & 63;
  const int fr = lane & 15, quad = lane >> 4;
  const int row = b * 4096 + nt * 64 + (w << 4) + fr;

  // load + normalize Q fragments (A-operand layout: m=fr, k=quad*8+j)
  const u16* qp = Q + (size_t)row * 768 + h * 64;
  bf16x8 qa0 = *(const bf16x8*)(qp + (quad << 3));
  bf16x8 qa1 = *(const bf16x8*)(qp + 32 + (quad << 3));
  float ss = 0.f;
  #pragma unroll
  for (int j = 0; j < 8; ++j) {
    float f0 = (float)qa0[j], f1 = (float)qa1[j];
    ss += f0 * f0 + f1 * f1;
  }
  ss += __shfl_xor(ss, 16);
  ss += __shfl_xor(ss, 32);
  float rn = rsqrtf(fmaxf(ss, 1e-24f));
  #pragma unroll
  for (int j = 0; j < 8; ++j) {
    qa0[j] = (__bf16)((float)qa0[j] * rn);
    qa1[j] = (__bf16)((float)qa1[j] * rn);
  }

  // S = q_norm . k  for all 512 banks; C layout: row(q)=quad*4+r, col(bank)=mc*16+fr
  f32x4 s[32];
  const u16* kbase = Kb + (size_t)h * 512 * 64;
  #pragma unroll
  for (int mc = 0; mc < 32; ++mc) {
    const u16* kp = kbase + (size_t)(mc * 16 + fr) * 64 + (quad << 3);
    bf16x8 k0 = *(const bf16x8*)kp;
    bf16x8 k1 = *(const bf16x8*)(kp + 32);
    f32x4 z = {0.f, 0.f, 0.f, 0.f};
    z = MFMA(qa0, k0, z);
    z = MFMA(qa1, k1, z);
    s[mc] = z;
  }

  // softmax over 512 (exp2 domain; log2e folded into K)
  float mx[4] = {-1e30f, -1e30f, -1e30f, -1e30f};
  #pragma unroll
  for (int mc = 0; mc < 32; ++mc)
    #pragma unroll
    for (int r = 0; r < 4; ++r) mx[r] = fmaxf(mx[r], s[mc][r]);
  #pragma unroll
  for (int r = 0; r < 4; ++r) {
    mx[r] = fmaxf(mx[r], __shfl_xor(mx[r], 1));
    mx[r] = fmaxf(mx[r], __shfl_xor(mx[r], 2));
    mx[r] = fmaxf(mx[r], __shfl_xor(mx[r], 4));
    mx[r] = fmaxf(mx[r], __shfl_xor(mx[r], 8));
  }
  float ls[4] = {0.f, 0.f, 0.f, 0.f};
  #pragma unroll
  for (int mc = 0; mc < 32; ++mc)
    #pragma unroll
    for (int r = 0; r < 4; ++r) {
      float p = __builtin_amdgcn_exp2f(s[mc][r] - mx[r]);
      s[mc][r] = p;
      ls[r] += p;
    }
  #pragma unroll
  for (int r = 0; r < 4; ++r) {
    ls[r] += __shfl_xor(ls[r], 1);
    ls[r] += __shfl_xor(ls[r], 2);
    ls[r] += __shfl_xor(ls[r], 4);
    ls[r] += __shfl_xor(ls[r], 8);
  }

  // O^T = V^T . P^T via LDS round-trip, 128-bank phases
  f32x4 oa[4] = {};
  u16* my = sp[w];
  const u16* vbase = Vt + (size_t)h * 64 * 512;
  for (int ph = 0; ph < 4; ++ph) {
    #pragma unroll
    for (int i = 0; i < 8; ++i) {
      int mc = ph * 8 + i;
      #pragma unroll
      for (int r = 0; r < 4; ++r)
        my[(quad * 4 + r) * 136 + i * 16 + fr] = f2bf(s[mc][r]);
    }
    #pragma unroll
    for (int ks = 0; ks < 4; ++ks) {
      bf16x8 pb = *(const bf16x8*)(my + fr * 136 + ks * 32 + (quad << 3));
      #pragma unroll
      for (int t = 0; t < 4; ++t) {
        const u16* vp = vbase + (size_t)(t * 16 + fr) * 512 + ph * 128 + ks * 32 + (quad << 3);
        bf16x8 va = *(const bf16x8*)vp;
        oa[t] = MFMA(va, pb, oa[t]);
      }
    }
  }

  // epilogue: scale by 1/l (transpose l across lanes via LDS), store bf16
  if (fr == 0) {
    #pragma unroll
    for (int r = 0; r < 4; ++r) lbuf[w][quad * 4 + r] = ls[r];
  }
  float rl = __builtin_amdgcn_rcpf(lbuf[w][fr]);
  u16* op = O + (size_t)row * 768 + h * 64 + (quad << 2);
  #pragma unroll
  for (int t = 0; t < 4; ++t) {
    ushort4 pk;
    pk.x = f2bf(oa[t][0] * rl);
    pk.y = f2bf(oa[t][1] * rl);
    pk.z = f2bf(oa[t][2] * rl);
    pk.w = f2bf(oa[t][3] * rl);
    *(ushort4*)(op + t * 16) = pk;
  }
}

extern "C" void kernel_launch(void* const* d_in, const int* in_sizes, int n_in,
                              void* d_out, int out_size, void* d_ws, size_t ws_size,
                              hipStream_t stream) {
  const float* x      = (const float*)d_in[0];  // (8,4096,768)
  const float* bank   = (const float*)d_in[1];  // (1,512,16)
  const float* Wq     = (const float*)d_in[2];  // (768,768)
  const float* Wkv    = (const float*)d_in[3];  // (16,1536)
  const float* Wlin   = (const float*)d_in[4];  // (768,768)
  const float* b_lin  = (const float*)d_in[5];  // (768,)
  const float* prelu  = (const float*)d_in[6];  // scalar
  const float* temp   = (const float*)d_in[7];  // (12,1,1)
  float* out = (float*)d_out;

  char* ws = (char*)d_ws;
  const size_t NELEM = 25165824;  // 8*4096*768
  u16* qbuf  = (u16*)ws;                          // 50,331,648 B (bf16 q)
  u16* xbuf  = (u16*)(ws + 50331648);             // 50,331,648 B (x bf16; aliased as O after GEMM1)
  u16* obuf  = xbuf;                              // alias (x dead after GEMM1)
  u16* wqt   = (u16*)(ws + 100663296);            // 1,179,648 B
  u16* wlt   = wqt + 589824;                      // 1,179,648 B
  u16* kbuf  = wlt + 589824;                      // 786,432 B
  u16* vtbuf = kbuf + 393216;                     // 786,432 B

  cvt_f32_bf16<<<4096, 256, 0, stream>>>(x, xbuf, (int)(NELEM / 4));
  transpose_cvt<<<dim3(24, 24), dim3(32, 8), 0, stream>>>(Wq, wqt, 768, 768);
  transpose_cvt<<<dim3(24, 24), dim3(32, 8), 0, stream>>>(Wlin, wlt, 768, 768);
  kv_prep<<<6144, 64, 0, stream>>>(bank, Wkv, temp, kbuf, vtbuf);
  gemm_bt<0><<<1536, 256, 0, stream>>>(xbuf, wqt, qbuf, 32768, 768, 768, nullptr, nullptr);
  attn_kern<<<6144, 256, 0, stream>>>(qbuf, kbuf, vtbuf, obuf);
  gemm_bt<1><<<1536, 256, 0, stream>>>(obuf, wlt, out, 32768, 768, 768, b_lin, prelu);
}

// Round 2
// 421.684 us; speedup vs baseline: 1.6372x; 1.6372x over previous
//
#include <hip/hip_runtime.h>
#include <cstdint>
#include <cstddef>

typedef unsigned short u16;
typedef __attribute__((ext_vector_type(8))) __bf16 bf16x8;
typedef __attribute__((ext_vector_type(4))) float f32x4;

#define MFMA(a, b, c) __builtin_amdgcn_mfma_f32_16x16x32_bf16(a, b, c, 0, 0, 0)

__device__ __forceinline__ u16 f2bf(float f) {
  union { float f; uint32_t u; } x; x.f = f;
  uint32_t r = x.u + 0x7fffu + ((x.u >> 16) & 1u);
  return (u16)(r >> 16);
}

__device__ __forceinline__ void gld16(const u16* g, u16* l) {
  __builtin_amdgcn_global_load_lds(
      (const __attribute__((address_space(1))) void*)g,
      (__attribute__((address_space(3))) void*)l, 16, 0, 0);
}

// ---------------- elementwise f32 -> bf16 convert ----------------
__global__ void cvt_f32_bf16(const float* __restrict__ src, u16* __restrict__ dst, int n4) {
  int i = blockIdx.x * blockDim.x + threadIdx.x;
  int stride = gridDim.x * blockDim.x;
  for (; i < n4; i += stride) {
    float4 v = ((const float4*)src)[i];
    ushort4 o;
    o.x = f2bf(v.x); o.y = f2bf(v.y); o.z = f2bf(v.z); o.w = f2bf(v.w);
    ((ushort4*)dst)[i] = o;
  }
}

// ---------------- transpose + convert: src (R x C) f32 -> dst (C x R) bf16 ----------------
__global__ void transpose_cvt(const float* __restrict__ src, u16* __restrict__ dst, int R, int C) {
  __shared__ float tile[32][33];
  int bx = blockIdx.x * 32, by = blockIdx.y * 32;
  int tx = threadIdx.x, ty = threadIdx.y;
  #pragma unroll
  for (int i = ty; i < 32; i += 8)
    tile[i][tx] = src[(size_t)(by + i) * C + bx + tx];
  __syncthreads();
  #pragma unroll
  for (int i = ty; i < 32; i += 8)
    dst[(size_t)(bx + i) * R + by + tx] = f2bf(tile[tx][i]);
}

// ---------------- KV prep: k normalized * temp * log2e -> (H,512,64); v -> V^T (H,64,512) ----------------
__global__ void kv_prep(const float* __restrict__ bank, const float* __restrict__ Wkv,
                        const float* __restrict__ temp, u16* __restrict__ K, u16* __restrict__ VT) {
  int m = blockIdx.x & 511, h = blockIdx.x >> 9;
  int j = threadIdx.x;  // 64 threads = d index
  const float* br = bank + m * 16;
  float kj = 0.f, vj = 0.f;
  #pragma unroll
  for (int f = 0; f < 16; ++f) {
    float bv = br[f];
    kj = fmaf(bv, Wkv[f * 1536 + h * 64 + j], kj);
    vj = fmaf(bv, Wkv[f * 1536 + 768 + h * 64 + j], vj);
  }
  float ss = kj * kj;
  #pragma unroll
  for (int o = 32; o; o >>= 1) ss += __shfl_xor(ss, o);
  float rn = rsqrtf(fmaxf(ss, 1e-24f));
  K[((size_t)h * 512 + m) * 64 + j] = f2bf(kj * rn * temp[h] * 1.4426950408889634f);
  VT[((size_t)h * 64 + j) * 512 + m] = f2bf(vj);
}

// ---------------- bf16 GEMM, A (MxK) row-major, BT (NxK) row-major ----------------
template <int MODE>
__global__ __launch_bounds__(256, 3) void gemm_bt(
    const u16* __restrict__ A, const u16* __restrict__ BT, void* __restrict__ Cout,
    int M, int N, int K, const float* __restrict__ bias, const float* __restrict__ prelu) {
  __shared__ u16 sA[128 * 32];
  __shared__ u16 sB[128 * 32];
  const int ntiles = N >> 7;
  const int m0 = (blockIdx.x / ntiles) << 7;
  const int n0 = (blockIdx.x % ntiles) << 7;
  const int tid = threadIdx.x;
  const int w = tid >> 6, lane = tid & 63;
  const int wm = (w >> 1) << 6, wn = (w & 1) << 6;
  const int srow = lane >> 2, scol = (lane & 3) << 3;
  const u16* ga = A + (size_t)(m0 + (w << 5) + srow) * K + scol;
  const u16* gb = BT + (size_t)(n0 + (w << 5) + srow) * K + scol;
  u16* la = sA + (w << 5) * 32;
  u16* lb = sB + (w << 5) * 32;
  const int fr = lane & 15, fq = (lane >> 4) << 3;
  f32x4 acc[4][4] = {};

  for (int k0 = 0; k0 < K; k0 += 32) {
    __syncthreads();
    gld16(ga + k0, la);
    gld16(ga + k0 + (size_t)16 * K, la + 16 * 32);
    gld16(gb + k0, lb);
    gld16(gb + k0 + (size_t)16 * K, lb + 16 * 32);
    __syncthreads();
    bf16x8 af[4], bfr[4];
    #pragma unroll
    for (int t = 0; t < 4; ++t) {
      af[t] = *(const bf16x8*)(sA + (wm + t * 16 + fr) * 32 + fq);
      bfr[t] = *(const bf16x8*)(sB + (wn + t * 16 + fr) * 32 + fq);
    }
    #pragma unroll
    for (int i = 0; i < 4; ++i)
      #pragma unroll
      for (int j = 0; j < 4; ++j)
        acc[i][j] = MFMA(af[i], bfr[j], acc[i][j]);
  }

  const int q = lane >> 4;
  float a = (MODE == 1) ? prelu[0] : 0.f;
  #pragma unroll
  for (int tm = 0; tm < 4; ++tm)
    #pragma unroll
    for (int tn = 0; tn < 4; ++tn) {
      int col = n0 + wn + tn * 16 + fr;
      float bv = (MODE == 1) ? bias[col] : 0.f;
      #pragma unroll
      for (int r = 0; r < 4; ++r) {
        int row = m0 + wm + tm * 16 + q * 4 + r;
        float v = acc[tm][tn][r];
        if (MODE == 1) {
          v += bv;
          v = v >= 0.f ? v : v * a;
          ((float*)Cout)[(size_t)row * N + col] = v;
        } else {
          ((u16*)Cout)[(size_t)row * N + col] = f2bf(v);
        }
      }
    }
}

// ---------------- fused cosine attention v2 ----------------
// S^T orientation: S^T = K·Q^T (A=K, B=Q-in-regs). C layout: col(lane&15)=qrow, row=key.
// Per block: 4 waves x 64 qrows = 256 rows of one head. K/V staged to LDS in 64-key
// chunks, double-buffered through registers (1 barrier/chunk). No max-subtraction:
// scores bounded by temp*log2e (cosine attention, temp folded into K).
// Q: (B*N,768) bf16 un-normalized. K: (H,512,64) bf16 (temp*log2e folded).
// VT: (H,64,512) bf16. O: (B*N,768) bf16.
__global__ __launch_bounds__(256, 2) void attn_kern(
    const u16* __restrict__ Q, const u16* __restrict__ Kb,
    const u16* __restrict__ Vt, u16* __restrict__ O) {
  __shared__ __align__(16) u16 sK[2][64 * 72];   // [chunk key][d + pad8]
  __shared__ __align__(16) u16 sV[2][64 * 72];   // [d][chunk key + pad8]
  __shared__ __align__(16) u16 pb_s[4][64 * 40]; // per-wave P^T stage: [qrow][32 keys + pad8]

  const int qb = blockIdx.x & 127;
  const int h = blockIdx.x >> 7;
  const int tid = threadIdx.x, w = tid >> 6, lane = tid & 63;
  const int fr = lane & 15, quad = lane >> 4;
  const int rowbase = qb * 256 + (w << 6);

  // ---- load + normalize Q for 4 row-groups (B-operand layout: n=fr, k=quad*8+j) ----
  bf16x8 qa[4][2];
  #pragma unroll
  for (int g = 0; g < 4; ++g) {
    const u16* qp = Q + (size_t)(rowbase + g * 16 + fr) * 768 + h * 64 + (quad << 3);
    qa[g][0] = *(const bf16x8*)qp;
    qa[g][1] = *(const bf16x8*)(qp + 32);
    float ss = 0.f;
    #pragma unroll
    for (int j = 0; j < 8; ++j) {
      float f0 = (float)qa[g][0][j], f1 = (float)qa[g][1][j];
      ss += f0 * f0 + f1 * f1;
    }
    ss += __shfl_xor(ss, 16);
    ss += __shfl_xor(ss, 32);
    float rn = rsqrtf(fmaxf(ss, 1e-24f));
    #pragma unroll
    for (int j = 0; j < 8; ++j) {
      qa[g][0][j] = (__bf16)((float)qa[g][0][j] * rn);
      qa[g][1][j] = (__bf16)((float)qa[g][1][j] * rn);
    }
  }

  // ---- staging machinery: 64-key chunk = 8KB K + 8KB V; 2 x 16B per thread each ----
  const u16* kg = Kb + (size_t)h * 512 * 64;
  const u16* vg = Vt + (size_t)h * 64 * 512;
  int4 kreg[2], vreg[2];
  auto load_chunk = [&](int c) {
    #pragma unroll
    for (int r = 0; r < 2; ++r) {
      int u = r * 256 + tid;
      kreg[r] = *(const int4*)(kg + (size_t)(c * 64 + (u >> 3)) * 64 + (u & 7) * 8);
      vreg[r] = *(const int4*)(vg + (size_t)(u >> 3) * 512 + c * 64 + (u & 7) * 8);
    }
  };
  auto store_chunk = [&](int buf) {
    #pragma unroll
    for (int r = 0; r < 2; ++r) {
      int u = r * 256 + tid;
      *(int4*)(sK[buf] + (u >> 3) * 72 + (u & 7) * 8) = kreg[r];
      *(int4*)(sV[buf] + (u >> 3) * 72 + (u & 7) * 8) = vreg[r];
    }
  };

  load_chunk(0);
  store_chunk(0);
  load_chunk(1);
  __syncthreads();

  f32x4 oa[4][4] = {};   // [g][d-tile] O^T accumulators
  float ls[4] = {0.f, 0.f, 0.f, 0.f};  // per-lane softmax-denominator partials per group
  u16* pw = pb_s[w];

  for (int c = 0; c < 8; ++c) {
    const int cb = c & 1;
    // stage chunk c+1 (regs -> LDS other buffer), prefetch chunk c+2
    if (c < 7) store_chunk((c + 1) & 1);
    if (c < 6) load_chunk(c + 2);

    // ---- S^T = K . Q^T over this chunk: tiles mt (16 keys each) ----
    f32x4 s[4][4];  // [g][mt]
    #pragma unroll
    for (int mt = 0; mt < 4; ++mt) {
      const u16* kp = sK[cb] + (mt * 16 + fr) * 72 + (quad << 3);
      bf16x8 ak0 = *(const bf16x8*)kp;
      bf16x8 ak1 = *(const bf16x8*)(kp + 32);
      #pragma unroll
      for (int g = 0; g < 4; ++g) {
        f32x4 z = {0.f, 0.f, 0.f, 0.f};
        z = MFMA(ak0, qa[g][0], z);
        z = MFMA(ak1, qa[g][1], z);
        s[g][mt] = z;
      }
    }
    // ---- exp2 (scores bounded; log2e*temp folded into K) + denominator ----
    #pragma unroll
    for (int g = 0; g < 4; ++g)
      #pragma unroll
      for (int mt = 0; mt < 4; ++mt)
        #pragma unroll
        for (int r = 0; r < 4; ++r) {
          float p = __builtin_amdgcn_exp2f(s[g][mt][r]);
          ls[g] += p;
          s[g][mt][r] = p;
        }
    // ---- PV: O^T += V^T . P^T, per 32-key step ----
    #pragma unroll
    for (int ks = 0; ks < 2; ++ks) {
      // stage P^T (lane's 4 regs = 4 consecutive keys of row g*16+fr)
      #pragma unroll
      for (int g = 0; g < 4; ++g)
        #pragma unroll
        for (int i = 0; i < 2; ++i) {
          f32x4 v = s[g][ks * 2 + i];
          uint32_t lo = (uint32_t)f2bf(v[0]) | ((uint32_t)f2bf(v[1]) << 16);
          uint32_t hi = (uint32_t)f2bf(v[2]) | ((uint32_t)f2bf(v[3]) << 16);
          uint2 pk = {lo, hi};
          *(uint2*)(pw + (g * 16 + fr) * 40 + i * 16 + (quad << 2)) = pk;
        }
      bf16x8 va[4], pbf[4];
      #pragma unroll
      for (int t = 0; t < 4; ++t)
        va[t] = *(const bf16x8*)(sV[cb] + (t * 16 + fr) * 72 + ks * 32 + (quad << 3));
      #pragma unroll
      for (int g = 0; g < 4; ++g)
        pbf[g] = *(const bf16x8*)(pw + (g * 16 + fr) * 40 + (quad << 3));
      #pragma unroll
      for (int g = 0; g < 4; ++g)
        #pragma unroll
        for (int t = 0; t < 4; ++t)
          oa[g][t] = MFMA(va[t], pbf[g], oa[g][t]);
    }
    __syncthreads();
  }

  // ---- epilogue: reduce denominators across quads, scale, store ----
  #pragma unroll
  for (int g = 0; g < 4; ++g) {
    float l = ls[g];
    l += __shfl_xor(l, 16);
    l += __shfl_xor(l, 32);
    float rl = __builtin_amdgcn_rcpf(l);
    u16* op = O + (size_t)(rowbase + g * 16 + fr) * 768 + h * 64 + (quad << 2);
    #pragma unroll
    for (int t = 0; t < 4; ++t) {
      ushort4 pk;
      pk.x = f2bf(oa[g][t][0] * rl);
      pk.y = f2bf(oa[g][t][1] * rl);
      pk.z = f2bf(oa[g][t][2] * rl);
      pk.w = f2bf(oa[g][t][3] * rl);
      *(ushort4*)(op + t * 16) = pk;
    }
  }
}

extern "C" void kernel_launch(void* const* d_in, const int* in_sizes, int n_in,
                              void* d_out, int out_size, void* d_ws, size_t ws_size,
                              hipStream_t stream) {
  const float* x      = (const float*)d_in[0];  // (8,4096,768)
  const float* bank   = (const float*)d_in[1];  // (1,512,16)
  const float* Wq     = (const float*)d_in[2];  // (768,768)
  const float* Wkv    = (const float*)d_in[3];  // (16,1536)
  const float* Wlin   = (const float*)d_in[4];  // (768,768)
  const float* b_lin  = (const float*)d_in[5];  // (768,)
  const float* prelu  = (const float*)d_in[6];  // scalar
  const float* temp   = (const float*)d_in[7];  // (12,1,1)
  float* out = (float*)d_out;

  char* ws = (char*)d_ws;
  const size_t NELEM = 25165824;  // 8*4096*768
  u16* qbuf  = (u16*)ws;                          // bf16 q
  u16* xbuf  = (u16*)(ws + 50331648);             // x bf16; aliased as O after GEMM1
  u16* obuf  = xbuf;
  u16* wqt   = (u16*)(ws + 100663296);
  u16* wlt   = wqt + 589824;
  u16* kbuf  = wlt + 589824;
  u16* vtbuf = kbuf + 393216;

  cvt_f32_bf16<<<4096, 256, 0, stream>>>(x, xbuf, (int)(NELEM / 4));
  transpose_cvt<<<dim3(24, 24), dim3(32, 8), 0, stream>>>(Wq, wqt, 768, 768);
  transpose_cvt<<<dim3(24, 24), dim3(32, 8), 0, stream>>>(Wlin, wlt, 768, 768);
  kv_prep<<<6144, 64, 0, stream>>>(bank, Wkv, temp, kbuf, vtbuf);
  gemm_bt<0><<<1536, 256, 0, stream>>>(xbuf, wqt, qbuf, 32768, 768, 768, nullptr, nullptr);
  attn_kern<<<1536, 256, 0, stream>>>(qbuf, kbuf, vtbuf, obuf);
  gemm_bt<1><<<1536, 256, 0, stream>>>(obuf, wlt, out, 32768, 768, 768, b_lin, prelu);
}